// Round 6
// baseline (464.970 us; speedup 1.0000x reference)
//
#include <hip/hip_runtime.h>
#include <hip/hip_bf16.h>

// GTLayer: AtomEncoder -> QKV -> sparse MHA (SDDMM + segment softmax + SpMM) -> out proj
// H=64, NH=8, DH=8. reshape(N, DH, NH) of row-major [N,64] => [n,d,h] = flat[n*64 + d*8 + h].
//
// Round-6: node_attn was VALU-issue bound (54% busy, ~60 instr/edge: 3 shuffles
// + 1.25 wave-wide exps + 2 scalar gathers per edge). Restructure: TRANSPOSED
// layout qT[n][h][d], kv[n][128] (k|v, [h][d]-major). Lane (e,h) owns edge-slot
// e, head h: 8 edges/wave-iter, 4 float4 gathers from ONE base (imm offsets),
// d-dot = 8 in-reg FMAs (no shuffles), per-lane online softmax (2 exps / 8
// edges). Flash-merge across e-slots once per node (3 shuffle rounds).

#define NPB 4  // waves (nodes) per 256-thread block in node_attn

// ---------------- encode: embedding sum + QKV GEMM (64 nodes/block) + degree ----
// Same compute as round-5; stores permuted to transposed layout:
// orig col = d*8+h  ->  tcol = h*8+d = ((col&7)<<3)|(col>>3).
__global__ void encode_gemm_kernel(const int* __restrict__ X,
                                   const float* __restrict__ atom_emb,
                                   const float* __restrict__ Wq, const float* __restrict__ bq,
                                   const float* __restrict__ Wk, const float* __restrict__ bk,
                                   const float* __restrict__ Wv, const float* __restrict__ bv,
                                   const int* __restrict__ row, int* __restrict__ deg,
                                   float* __restrict__ qT, float* __restrict__ kv,
                                   int N, int E)
{
    __shared__ float sH[64][65];  // [node-in-tile][dim], pad 65 => conflict-free

    const int tid = threadIdx.x;

    // degree histogram (independent; atomics fire-and-forget)
    for (int e = blockIdx.x * 256 + tid; e < E; e += gridDim.x * 256)
        atomicAdd(&deg[row[e]], 1);

    // embedding phase: wave w -> nodes w*16..w*16+15, lane = dim
    const int wv = tid >> 6, lane = tid & 63;
    const int nbase = blockIdx.x * 64;
    const int offs[9] = {0, 119, 124, 136, 148, 158, 164, 170, 172};
    for (int nn = 0; nn < 16; ++nn) {
        const int nloc = wv * 16 + nn;
        const int n = nbase + nloc;
        float hval = 0.f;
        if (n < N) {
#pragma unroll
            for (int f = 0; f < 9; ++f)
                hval += atom_emb[(size_t)(X[n * 9 + f] + offs[f]) * 64 + lane];
        }
        sH[nloc][lane] = hval;
    }
    __syncthreads();

    // GEMM phase: thread tile = nodes ng*4..+3  x  orig cols {16j+cg, j=0..11 sets}
    const int ng = tid >> 4;
    const int cg = tid & 15;

    float acc[4][12];
#pragma unroll
    for (int j = 0; j < 4; ++j) {
        const float bjq = bq[16 * j + cg];
        const float bjk = bk[16 * j + cg];
        const float bjv = bv[16 * j + cg];
#pragma unroll
        for (int i = 0; i < 4; ++i) {
            acc[i][j] = bjq;
            acc[i][4 + j] = bjk;
            acc[i][8 + j] = bjv;
        }
    }

#pragma unroll 4
    for (int kk = 0; kk < 64; ++kk) {
        float w[12];
#pragma unroll
        for (int j = 0; j < 4; ++j) {
            w[j]     = Wq[kk * 64 + 16 * j + cg];  // L1-resident, coalesced broadcast
            w[4 + j] = Wk[kk * 64 + 16 * j + cg];
            w[8 + j] = Wv[kk * 64 + 16 * j + cg];
        }
        const float h0 = sH[ng * 4 + 0][kk];
        const float h1 = sH[ng * 4 + 1][kk];
        const float h2 = sH[ng * 4 + 2][kk];
        const float h3 = sH[ng * 4 + 3][kk];
#pragma unroll
        for (int j = 0; j < 12; ++j) {
            acc[0][j] = fmaf(h0, w[j], acc[0][j]);
            acc[1][j] = fmaf(h1, w[j], acc[1][j]);
            acc[2][j] = fmaf(h2, w[j], acc[2][j]);
            acc[3][j] = fmaf(h3, w[j], acc[3][j]);
        }
    }

    const float scaling = 0.35355339059327373f;  // 8^-0.5, applied after bias (ref order)
#pragma unroll
    for (int i = 0; i < 4; ++i) {
        const int n = nbase + ng * 4 + i;
        if (n < N) {
#pragma unroll
            for (int j = 0; j < 4; ++j) {
                const int col = 16 * j + cg;
                const int tcol = ((col & 7) << 3) | (col >> 3);  // h*8+d
                qT[(size_t)n * 64 + tcol] = acc[i][j] * scaling;
                kv[(size_t)n * 128 + tcol] = acc[i][4 + j];        // k half
                kv[(size_t)n * 128 + 64 + tcol] = acc[i][8 + j];   // v half
            }
        }
    }
}

// ---------------- CSR build ----------------
__global__ void scan_local_kernel(const int* __restrict__ deg, int* __restrict__ offs,
                                  int* __restrict__ tsum, int N)
{
    __shared__ int lds[256];
    const int t = threadIdx.x;
    const int tbase = blockIdx.x * 1024;

    int v0[4];
    int s = 0;
#pragma unroll
    for (int i = 0; i < 4; ++i) {
        int idx = tbase + t * 4 + i;
        v0[i] = (idx < N) ? deg[idx] : 0;
        s += v0[i];
    }
    lds[t] = s;
    __syncthreads();
    for (int off = 1; off < 256; off <<= 1) {
        int x = (t >= off) ? lds[t - off] : 0;
        __syncthreads();
        lds[t] += x;
        __syncthreads();
    }
    if (t == 255) tsum[blockIdx.x] = lds[255];
    int run = (t > 0) ? lds[t - 1] : 0;
#pragma unroll
    for (int i = 0; i < 4; ++i) {
        int idx = tbase + t * 4 + i;
        if (idx < N) offs[idx] = run;
        run += v0[i];
    }
}

__global__ void add_base_kernel(int* __restrict__ offs, const int* __restrict__ tsum,
                                int* __restrict__ cursor, int N)
{
    __shared__ int red[256];
    const int b = blockIdx.x;
    const int t = threadIdx.x;

    int s = 0;
    for (int i = t; i < b; i += 256) s += tsum[i];  // exclusive: tiles 0..b-1
    red[t] = s;
    __syncthreads();
    for (int off = 128; off > 0; off >>= 1) {
        if (t < off) red[t] += red[t + off];
        __syncthreads();
    }
    const int S = red[0];

    const int base = b * 1024;
    for (int i = t; i < 1024; i += 256) {
        int idx = base + i;
        if (idx < N) {
            int o = offs[idx] + S;
            offs[idx] = o;
            cursor[idx] = o;
        }
    }
}

__global__ void scatter_kernel(const int* __restrict__ row, const int* __restrict__ col,
                               int* __restrict__ cursor, int* __restrict__ csr_col, int E)
{
    int e = blockIdx.x * 256 + threadIdx.x;
    if (e < E) {
        int pos = atomicAdd(&cursor[row[e]], 1);
        csr_col[pos] = col[e];
    }
}

// ---------------- fused per-node attention + out-proj ----------------
// Lane (e,h): e = lane>>3 edge-slot, h = lane&7 head. 8 edges per iteration.
// Per-lane online softmax over its edge subset; flash-merge across e-slots at end.
__global__ void node_attn_kernel(const float* __restrict__ qT, const float* __restrict__ kv,
                                 const int* __restrict__ offs, const int* __restrict__ deg,
                                 const int* __restrict__ csr_col,
                                 const float* __restrict__ Wo, const float* __restrict__ bo,
                                 float* __restrict__ out, int N)
{
    __shared__ float sh[NPB][64];

    const int tid = threadIdx.x;
    const int g = tid >> 6;
    const int lane = tid & 63;
    const int eslot = lane >> 3;
    const int h = lane & 7;
    const int n = blockIdx.x * NPB + g;

    if (n < N) {
        const int base = offs[n];
        const int d = deg[n];

        // q fragment for head h (same for all e-slots; L1 broadcast lines)
        const float4 qa = *(const float4*)&qT[(size_t)n * 64 + h * 8];
        const float4 qb = *(const float4*)&qT[(size_t)n * 64 + h * 8 + 4];

        float m = -3.4e38f, sumP = 0.f;
        float a0 = 0.f, a1 = 0.f, a2 = 0.f, a3 = 0.f;
        float a4 = 0.f, a5 = 0.f, a6 = 0.f, a7 = 0.f;

        for (int j0 = 0; j0 < d; j0 += 8) {
            const int myj = j0 + eslot;
            const bool valid = myj < d;
            const int c = csr_col[base + (valid ? myj : j0)];
            const float* kvb = kv + (size_t)c * 128 + h * 8;  // one base, imm offsets
            const float4 ka = *(const float4*)(kvb + 0);
            const float4 kb = *(const float4*)(kvb + 4);
            const float4 va = *(const float4*)(kvb + 64);
            const float4 vb = *(const float4*)(kvb + 68);

            float s = qa.x * ka.x + qa.y * ka.y + qa.z * ka.z + qa.w * ka.w
                    + qb.x * kb.x + qb.y * kb.y + qb.z * kb.z + qb.w * kb.w;
            s = valid ? s : -3.4e38f;

            const float mNew = fmaxf(m, s);
            const float corr = __expf(m - mNew);       // 1 on first iter (0-0)
            const float p = valid ? __expf(s - mNew) : 0.f;
            sumP = fmaf(sumP, corr, p);
            a0 = fmaf(a0, corr, p * va.x);
            a1 = fmaf(a1, corr, p * va.y);
            a2 = fmaf(a2, corr, p * va.z);
            a3 = fmaf(a3, corr, p * va.w);
            a4 = fmaf(a4, corr, p * vb.x);
            a5 = fmaf(a5, corr, p * vb.y);
            a6 = fmaf(a6, corr, p * vb.z);
            a7 = fmaf(a7, corr, p * vb.w);
            m = mNew;
        }

        // flash-merge across e-slots (lane bits 3..5); all lanes end with head totals
#pragma unroll
        for (int mask = 8; mask <= 32; mask <<= 1) {
            const float mo = __shfl_xor(m, mask, 64);
            const float mN = fmaxf(m, mo);
            const float cs = __expf(m - mN);
            const float co = __expf(mo - mN);
            const float so = __shfl_xor(sumP, mask, 64);
            sumP = sumP * cs + so * co;
            float t;
            t = __shfl_xor(a0, mask, 64); a0 = a0 * cs + t * co;
            t = __shfl_xor(a1, mask, 64); a1 = a1 * cs + t * co;
            t = __shfl_xor(a2, mask, 64); a2 = a2 * cs + t * co;
            t = __shfl_xor(a3, mask, 64); a3 = a3 * cs + t * co;
            t = __shfl_xor(a4, mask, 64); a4 = a4 * cs + t * co;
            t = __shfl_xor(a5, mask, 64); a5 = a5 * cs + t * co;
            t = __shfl_xor(a6, mask, 64); a6 = a6 * cs + t * co;
            t = __shfl_xor(a7, mask, 64); a7 = a7 * cs + t * co;
            m = mN;
        }

        if (eslot == 0) {  // one writer per head; sh layout = orig col d*8+h
            const float inv = (d > 0) ? 1.f / sumP : 0.f;
            sh[g][0 * 8 + h] = a0 * inv;
            sh[g][1 * 8 + h] = a1 * inv;
            sh[g][2 * 8 + h] = a2 * inv;
            sh[g][3 * 8 + h] = a3 * inv;
            sh[g][4 * 8 + h] = a4 * inv;
            sh[g][5 * 8 + h] = a5 * inv;
            sh[g][6 * 8 + h] = a6 * inv;
            sh[g][7 * 8 + h] = a7 * inv;
        }
    }
    __syncthreads();

    if (n < N) {
        float o = bo[lane];
#pragma unroll
        for (int i = 0; i < 64; ++i)
            o = fmaf(sh[g][i], Wo[i * 64 + lane], o);  // Wo: 16KB, L1-resident
        out[(size_t)n * 64 + lane] = o;
    }
}

extern "C" void kernel_launch(void* const* d_in, const int* in_sizes, int n_in,
                              void* d_out, int out_size, void* d_ws, size_t ws_size,
                              hipStream_t stream)
{
    const int*   X        = (const int*)d_in[0];
    const int*   row      = (const int*)d_in[1];
    const int*   col      = (const int*)d_in[2];
    const float* atom_emb = (const float*)d_in[3];
    const float* Wq       = (const float*)d_in[4];
    const float* bq       = (const float*)d_in[5];
    const float* Wk       = (const float*)d_in[6];
    const float* bk       = (const float*)d_in[7];
    const float* Wv       = (const float*)d_in[8];
    const float* bv       = (const float*)d_in[9];
    const float* Wo       = (const float*)d_in[10];
    const float* bo       = (const float*)d_in[11];

    const int N = in_sizes[0] / 9;
    const int E = in_sizes[1];
    const int nTiles = (N + 1023) / 1024;

    // Workspace layout: qT | kv | offs | deg | cursor | tsum | csr_col
    float* qT  = (float*)d_ws;
    float* kv  = qT + (size_t)N * 64;
    int* offs    = (int*)(kv + (size_t)N * 128);     // N
    int* deg     = offs + N;                         // N
    int* cursor  = deg + N;                          // N
    int* tsum    = cursor + N;                       // nTiles (<=1024)
    int* csr_col = tsum + 1024;                      // E
    // total ~ (19.2M + 0.3M + 1.6M)*4B ~ 85 MB

    // ws is poisoned 0xAA before every timed call: zero the histogram.
    hipMemsetAsync(deg, 0, (size_t)N * sizeof(int), stream);

    encode_gemm_kernel<<<(N + 63) / 64, 256, 0, stream>>>(
        X, atom_emb, Wq, bq, Wk, bk, Wv, bv, row, deg, qT, kv, N, E);

    scan_local_kernel<<<nTiles, 256, 0, stream>>>(deg, offs, tsum, N);
    add_base_kernel<<<nTiles, 256, 0, stream>>>(offs, tsum, cursor, N);
    scatter_kernel<<<(E + 255) / 256, 256, 0, stream>>>(row, col, cursor, csr_col, E);

    node_attn_kernel<<<(N + NPB - 1) / NPB, 256, 0, stream>>>(
        qT, kv, offs, deg, csr_col, Wo, bo, (float*)d_out, N);
}